// Round 1
// baseline (686.784 us; speedup 1.0000x reference)
//
#include <hip/hip_runtime.h>
#include <stdint.h>

// ---------------------------------------------------------------------------
// NIVR: coord-MLP over 512x512 grid.
//   time branch (exact fp32, 1 block)   -> tvec[512]
//   posenc tables (exact fp32)          -> Tx[512][512], Ty[512][512]
//   W2f -> bf16, pre-swizzled per-K-step LDS image -> W2s
//   main: h1 = relu(Tx[x]+Ty[y]+tvec) on the fly; layer2 via MFMA bf16
//         16x16x32; fused layer3 epilogue via quad shuffles. Output [3][N].
// ---------------------------------------------------------------------------

typedef short bf16x8 __attribute__((ext_vector_type(8)));
typedef float f32x4 __attribute__((ext_vector_type(4)));

#define PI_F 3.14159265358979323846f
#define SIDE 512
#define NPIX (SIDE * SIDE)

__device__ __forceinline__ unsigned short f2bf(float f) {
  // round-to-nearest-even fp32 -> bf16 (no NaN handling needed here)
  unsigned int u = __float_as_uint(f);
  u += 0x7fffu + ((u >> 16) & 1u);
  return (unsigned short)(u >> 16);
}

__device__ __forceinline__ void gl_lds16(const void* g, void* l) {
  // async global->LDS, 16B/lane; LDS dest = uniform base + lane*16
  __builtin_amdgcn_global_load_lds(
      (__attribute__((address_space(1))) unsigned int*)g,
      (__attribute__((address_space(3))) unsigned int*)l, 16, 0, 0);
}

// ---------------------------------------------------------------------------
// Kernel 1: time branch. t = idx/300; r = posenc(t, 16) (sin x16, cos x16);
// h = relu(r@W1p + b1p); phi = h@W2p + b2p; tvec = b1f + phi @ W1f[40:168].
// ---------------------------------------------------------------------------
__global__ void time_kernel(const float* __restrict__ W1p, const float* __restrict__ b1p,
                            const float* __restrict__ W2p, const float* __restrict__ b2p,
                            const float* __restrict__ W1f, const float* __restrict__ b1f,
                            const int* __restrict__ idx, float* __restrict__ tvec) {
  __shared__ float r_s[32];
  __shared__ float h_s[256];
  __shared__ float phi_s[128];
  const int t = threadIdx.x;
  const float tt = (float)idx[0] / 300.0f;
  if (t < 16) {
    float ang = tt * ldexpf(PI_F, t);   // (2^l * pi) exact scaling of fp32 pi
    r_s[t] = sinf(ang);
    r_s[16 + t] = cosf(ang);
  }
  __syncthreads();
  if (t < 256) {
    float a = b1p[t];
#pragma unroll
    for (int i = 0; i < 32; ++i) a += r_s[i] * W1p[i * 256 + t];
    h_s[t] = fmaxf(a, 0.f);
  }
  __syncthreads();
  if (t < 128) {
    float a = b2p[t];
    for (int i = 0; i < 256; ++i) a += h_s[i] * W2p[i * 128 + t];
    phi_s[t] = a;
  }
  __syncthreads();
  {
    float a = b1f[t];
    for (int p = 0; p < 128; ++p) a += phi_s[p] * W1f[(40 + p) * 512 + t];
    tvec[t] = a;
  }
}

// ---------------------------------------------------------------------------
// Kernel 2: posenc tables. For value v (0..511), u = v/512:
//   enc[0..9]=sin(u*2^l*pi), enc[10..19]=cos(...)
//   Tx[v][k] = sum_l enc[l]*W1f[l][k];  Ty[v][k] = sum_l enc[l]*W1f[20+l][k]
// ---------------------------------------------------------------------------
__global__ void tables_kernel(const float* __restrict__ W1f,
                              float* __restrict__ Tx, float* __restrict__ Ty) {
  __shared__ float enc[20];
  const int v = blockIdx.x, k = threadIdx.x;
  if (k < 10) {
    float u = (float)v / 512.0f;
    float ang = u * ldexpf(PI_F, k);
    enc[k] = sinf(ang);
    enc[10 + k] = cosf(ang);
  }
  __syncthreads();
  float ax = 0.f, ay = 0.f;
#pragma unroll
  for (int l = 0; l < 20; ++l) {
    ax += enc[l] * W1f[l * 512 + k];
    ay += enc[l] * W1f[(20 + l) * 512 + k];
  }
  Tx[v * 512 + k] = ax;
  Ty[v * 512 + k] = ay;
}

// ---------------------------------------------------------------------------
// Kernel 3: W2f (fp32 [512][512], K-major) -> bf16 swizzled into the exact
// per-K-step B LDS image:
//   W2s[(((ks*32 + nt)*4 + q)*16 + ni)*8 + j] = bf16(W2f[ks*32+q*8+j][nt*16+ni])
// so each 32KB K-step slab is a contiguous copy, and lane l of the MFMA wave
// reads its B fragment (B[k=q*8+j][n=lane&15]) as one ds_read_b128.
// ---------------------------------------------------------------------------
__global__ void w2s_kernel(const float* __restrict__ W2f, unsigned short* __restrict__ W2s) {
  const int id = blockIdx.x * 512 + threadIdx.x;
  const int j = id & 7;
  const int ni = (id >> 3) & 15;
  const int q = (id >> 7) & 3;
  const int nt = (id >> 9) & 31;
  const int ks = id >> 14;
  const int k = ks * 32 + q * 8 + j;
  const int n = nt * 16 + ni;
  W2s[id] = f2bf(W2f[k * 512 + n]);
}

// ---------------------------------------------------------------------------
// Kernel 4: main fused kernel.
// Block = 512 threads (8 waves), BM=64 pixels (8x8 patch), BN=512 (full),
// K=512 in 16 steps of 32. Wave w owns N-slice [w*64, w*64+64).
// A-step tile (64x32 bf16, frag-swizzled, 4KB) written by the 64 threads whose
// k-block matches; B-step (32KB) staged contiguously via global_load_lds.
// Epilogue: relu(acc + b2f) -> layer3 partials in regs -> quad butterfly
// shuffle -> LDS partial[8][64][3] -> final sum + b3f -> out[c][n].
// ---------------------------------------------------------------------------
__global__ __launch_bounds__(512, 4) void main_kernel(
    const float* __restrict__ Tx, const float* __restrict__ Ty,
    const float* __restrict__ tvec, const unsigned short* __restrict__ W2s,
    const float* __restrict__ b2f, const float* __restrict__ W3f,
    const float* __restrict__ b3f, float* __restrict__ out) {
  __shared__ __attribute__((aligned(16))) unsigned short Astep[64 * 32];   // 4KB
  __shared__ __attribute__((aligned(16))) unsigned short Bbuf[32 * 512];   // 32KB
  __shared__ float part[8][64][3];                                         // 6KB

  const int t = threadIdx.x;
  const int w = t >> 6;            // wave id 0..7  (N-slice)
  const int lane = t & 63;
  const int q = lane >> 4;         // k-quad / row-quad
  const int lr = lane & 15;
  const int m = t >> 3;            // pixel 0..63 for A staging
  const int kb = t & 7;            // 64-wide k-block this thread stages
  const int mt_m = m >> 4, mr_m = m & 15;
  const int x0 = blockIdx.x * 8, y0 = blockIdx.y * 8;
  const int xi = x0 + (m >> 3), yi = y0 + (m & 7);

  const float* txp = Tx + xi * 512 + kb * 64;
  const float* typ = Ty + yi * 512 + kb * 64;
  const float* tvp = tvec + kb * 64;

  f32x4 acc[4][4];
#pragma unroll
  for (int i = 0; i < 4; ++i)
#pragma unroll
    for (int j2 = 0; j2 < 4; ++j2) acc[i][j2] = (f32x4){0.f, 0.f, 0.f, 0.f};

#pragma unroll
  for (int ks = 0; ks < 16; ++ks) {
    // ---- stage A(ks): 64 threads (one per pixel) each write 32 bf16 ----
    if (kb == (ks >> 1)) {
      const int kh = (ks & 1) * 32;
#pragma unroll
      for (int qq = 0; qq < 4; ++qq) {
        float4 a0 = *(const float4*)(txp + kh + qq * 8);
        float4 a1 = *(const float4*)(txp + kh + qq * 8 + 4);
        float4 b0 = *(const float4*)(typ + kh + qq * 8);
        float4 b1 = *(const float4*)(typ + kh + qq * 8 + 4);
        float4 c0 = *(const float4*)(tvp + kh + qq * 8);
        float4 c1 = *(const float4*)(tvp + kh + qq * 8 + 4);
        float v0 = fmaxf(a0.x + b0.x + c0.x, 0.f);
        float v1 = fmaxf(a0.y + b0.y + c0.y, 0.f);
        float v2 = fmaxf(a0.z + b0.z + c0.z, 0.f);
        float v3 = fmaxf(a0.w + b0.w + c0.w, 0.f);
        float v4 = fmaxf(a1.x + b1.x + c1.x, 0.f);
        float v5 = fmaxf(a1.y + b1.y + c1.y, 0.f);
        float v6 = fmaxf(a1.z + b1.z + c1.z, 0.f);
        float v7 = fmaxf(a1.w + b1.w + c1.w, 0.f);
        uint4 pk;
        pk.x = (unsigned)f2bf(v0) | ((unsigned)f2bf(v1) << 16);
        pk.y = (unsigned)f2bf(v2) | ((unsigned)f2bf(v3) << 16);
        pk.z = (unsigned)f2bf(v4) | ((unsigned)f2bf(v5) << 16);
        pk.w = (unsigned)f2bf(v6) | ((unsigned)f2bf(v7) << 16);
        *(uint4*)&Astep[((mt_m * 4 + qq) * 16 + mr_m) * 8] = pk;
      }
    }
    // ---- stage B(ks): 32KB contiguous; wave w copies 4 x 1KB chunks ----
    {
      const char* gsrc = (const char*)(W2s + ks * 16384);
#pragma unroll
      for (int i = 0; i < 4; ++i) {
        const int off = (w * 4 + i) * 1024;
        gl_lds16(gsrc + off + lane * 16, ((char*)Bbuf) + off);
      }
    }
    __syncthreads();
    // ---- MFMA: A frag lane l = A[m=lr][k=q*8+j]; B frag = B[k=q*8+j][n=lr]
    bf16x8 af[4];
#pragma unroll
    for (int mt = 0; mt < 4; ++mt)
      af[mt] = *(const bf16x8*)&Astep[((mt * 4 + q) * 16 + lr) * 8];
#pragma unroll
    for (int nt = 0; nt < 4; ++nt) {
      bf16x8 bfr = *(const bf16x8*)&Bbuf[(((w * 4 + nt) * 4 + q) * 16 + lr) * 8];
#pragma unroll
      for (int mt = 0; mt < 4; ++mt)
        acc[mt][nt] =
            __builtin_amdgcn_mfma_f32_16x16x32_bf16(af[mt], bfr, acc[mt][nt], 0, 0, 0);
    }
    __syncthreads();
  }

  // ---- epilogue: h2 = relu(acc + b2f); rgb partial = h2 @ W3f (k-slice) ----
  // lane holds rows mt*16 + q*4 + r, cols k = w*64 + nt*16 + lr
  float w3v[4][3];
  float bb2[4];
#pragma unroll
  for (int nt = 0; nt < 4; ++nt) {
    const int k = w * 64 + nt * 16 + lr;
    bb2[nt] = b2f[k];
    w3v[nt][0] = W3f[k * 3 + 0];
    w3v[nt][1] = W3f[k * 3 + 1];
    w3v[nt][2] = W3f[k * 3 + 2];
  }
#pragma unroll
  for (int half = 0; half < 2; ++half) {
    float v[2][4][3];
#pragma unroll
    for (int mi = 0; mi < 2; ++mi)
#pragma unroll
      for (int r = 0; r < 4; ++r)
#pragma unroll
        for (int c = 0; c < 3; ++c) v[mi][r][c] = 0.f;
#pragma unroll
    for (int mi = 0; mi < 2; ++mi) {
      const int mt = half * 2 + mi;
#pragma unroll
      for (int r = 0; r < 4; ++r) {
#pragma unroll
        for (int nt = 0; nt < 4; ++nt) {
          float h2 = fmaxf(acc[mt][nt][r] + bb2[nt], 0.f);
          v[mi][r][0] += h2 * w3v[nt][0];
          v[mi][r][1] += h2 * w3v[nt][1];
          v[mi][r][2] += h2 * w3v[nt][2];
        }
      }
    }
    // butterfly over the 16 lanes sharing the same row-quad (bits 0..3)
#pragma unroll
    for (int d = 1; d < 16; d <<= 1) {
#pragma unroll
      for (int mi = 0; mi < 2; ++mi)
#pragma unroll
        for (int r = 0; r < 4; ++r)
#pragma unroll
          for (int c = 0; c < 3; ++c)
            v[mi][r][c] += __shfl_xor(v[mi][r][c], d, 64);
    }
    if (lr == 0) {
#pragma unroll
      for (int mi = 0; mi < 2; ++mi)
#pragma unroll
        for (int r = 0; r < 4; ++r) {
          const int row = (half * 2 + mi) * 16 + q * 4 + r;
#pragma unroll
          for (int c = 0; c < 3; ++c) part[w][row][c] = v[mi][r][c];
        }
    }
  }
  __syncthreads();
  if (t < 192) {
    const int mm = t / 3, c = t - mm * 3;
    float s = b3f[c];
#pragma unroll
    for (int ww = 0; ww < 8; ++ww) s += part[ww][mm][c];
    const int n = (x0 + (mm >> 3)) * 512 + (y0 + (mm & 7));
    out[c * NPIX + n] = s;
  }
}

// ---------------------------------------------------------------------------
// Inputs (setup_inputs order):
// 0 coords (unused, grid is analytic), 1 W1p, 2 b1p, 3 W2p, 4 b2p,
// 5 W1f, 6 b1f, 7 W2f, 8 b2f, 9 W3f, 10 b3f, 11 idx (int)
// ---------------------------------------------------------------------------
extern "C" void kernel_launch(void* const* d_in, const int* in_sizes, int n_in,
                              void* d_out, int out_size, void* d_ws, size_t ws_size,
                              hipStream_t stream) {
  const float* W1p = (const float*)d_in[1];
  const float* b1p = (const float*)d_in[2];
  const float* W2p = (const float*)d_in[3];
  const float* b2p = (const float*)d_in[4];
  const float* W1f = (const float*)d_in[5];
  const float* b1f = (const float*)d_in[6];
  const float* W2f = (const float*)d_in[7];
  const float* b2f = (const float*)d_in[8];
  const float* W3f = (const float*)d_in[9];
  const float* b3f = (const float*)d_in[10];
  const int* idx = (const int*)d_in[11];
  float* out = (float*)d_out;

  char* ws = (char*)d_ws;
  float* Tx = (float*)ws;                                   // 1 MB
  float* Ty = (float*)(ws + (1u << 20));                    // 1 MB
  float* tvec = (float*)(ws + (2u << 20));                  // 2 KB
  unsigned short* W2s = (unsigned short*)(ws + (2u << 20) + 8192);  // 512 KB

  hipLaunchKernelGGL(time_kernel, dim3(1), dim3(512), 0, stream,
                     W1p, b1p, W2p, b2p, W1f, b1f, idx, tvec);
  hipLaunchKernelGGL(tables_kernel, dim3(512), dim3(512), 0, stream, W1f, Tx, Ty);
  hipLaunchKernelGGL(w2s_kernel, dim3(512), dim3(512), 0, stream, W2f, W2s);
  hipLaunchKernelGGL(main_kernel, dim3(64, 64), dim3(512), 0, stream,
                     Tx, Ty, tvec, W2s, b2f, W3f, b3f, out);
}

// Round 2
// 303.859 us; speedup vs baseline: 2.2602x; 2.2602x over previous
//
#include <hip/hip_runtime.h>
#include <stdint.h>

// ---------------------------------------------------------------------------
// NIVR: coord-MLP over 512x512 grid.
//   time branch (exact fp32, 1 block)   -> tvec[512]
//   posenc tables (exact fp32)          -> Tx[512][512], Ty[512][512]
//   W2f -> bf16, pre-swizzled per-K-step LDS image -> W2s
//   main: h1 = relu(Tx[x]+Ty[y]+tvec) on the fly; layer2 via MFMA bf16
//         16x16x32; fused layer3 epilogue via shuffles. Output [3][N].
//
// R2 changes vs R1 (which spilled: WRITE_SIZE 74MB, MfmaUtil 8.9%):
//  - A-staging spread over all 512 threads (4 vals each, coalesced) instead
//    of 8 divergent lanes/wave doing 24 scattered loads.
//  - Double-buffered A and B with ONE barrier/step; B prefetch for step ks+1
//    is issued right AFTER the barrier at step ks, so the mandatory vmcnt(0)
//    drain at the next barrier finds it already landed (m97-stall avoidance).
//  - Live register set kept < 128 (launch_bounds(512,4) cap) => no scratch.
//  - Output writes: one wave per RGB plane chunk (contiguous).
// ---------------------------------------------------------------------------

typedef short bf16x8 __attribute__((ext_vector_type(8)));
typedef float f32x4 __attribute__((ext_vector_type(4)));

#define PI_F 3.14159265358979323846f
#define SIDE 512
#define NPIX (SIDE * SIDE)

__device__ __forceinline__ unsigned short f2bf(float f) {
  unsigned int u = __float_as_uint(f);
  u += 0x7fffu + ((u >> 16) & 1u);
  return (unsigned short)(u >> 16);
}

__device__ __forceinline__ void gl_lds16(const void* g, void* l) {
  __builtin_amdgcn_global_load_lds(
      (__attribute__((address_space(1))) unsigned int*)g,
      (__attribute__((address_space(3))) unsigned int*)l, 16, 0, 0);
}

// ---------------------------------------------------------------------------
// Kernel 1: time branch (exact fp32).
// ---------------------------------------------------------------------------
__global__ void time_kernel(const float* __restrict__ W1p, const float* __restrict__ b1p,
                            const float* __restrict__ W2p, const float* __restrict__ b2p,
                            const float* __restrict__ W1f, const float* __restrict__ b1f,
                            const int* __restrict__ idx, float* __restrict__ tvec) {
  __shared__ float r_s[32];
  __shared__ float h_s[256];
  __shared__ float phi_s[128];
  const int t = threadIdx.x;
  const float tt = (float)idx[0] / 300.0f;
  if (t < 16) {
    float ang = tt * ldexpf(PI_F, t);
    r_s[t] = sinf(ang);
    r_s[16 + t] = cosf(ang);
  }
  __syncthreads();
  if (t < 256) {
    float a = b1p[t];
#pragma unroll
    for (int i = 0; i < 32; ++i) a += r_s[i] * W1p[i * 256 + t];
    h_s[t] = fmaxf(a, 0.f);
  }
  __syncthreads();
  if (t < 128) {
    float a = b2p[t];
    for (int i = 0; i < 256; ++i) a += h_s[i] * W2p[i * 128 + t];
    phi_s[t] = a;
  }
  __syncthreads();
  {
    float a = b1f[t];
    for (int p = 0; p < 128; ++p) a += phi_s[p] * W1f[(40 + p) * 512 + t];
    tvec[t] = a;
  }
}

// ---------------------------------------------------------------------------
// Kernel 2: posenc tables (exact fp32).
// ---------------------------------------------------------------------------
__global__ void tables_kernel(const float* __restrict__ W1f,
                              float* __restrict__ Tx, float* __restrict__ Ty) {
  __shared__ float enc[20];
  const int v = blockIdx.x, k = threadIdx.x;
  if (k < 10) {
    float u = (float)v / 512.0f;
    float ang = u * ldexpf(PI_F, k);
    enc[k] = sinf(ang);
    enc[10 + k] = cosf(ang);
  }
  __syncthreads();
  float ax = 0.f, ay = 0.f;
#pragma unroll
  for (int l = 0; l < 20; ++l) {
    ax += enc[l] * W1f[l * 512 + k];
    ay += enc[l] * W1f[(20 + l) * 512 + k];
  }
  Tx[v * 512 + k] = ax;
  Ty[v * 512 + k] = ay;
}

// ---------------------------------------------------------------------------
// Kernel 3: W2f -> bf16, per-K-step frag-swizzled LDS image.
//   W2s[(((ks*32 + nt)*4 + q)*16 + ni)*8 + j] = bf16(W2f[ks*32+q*8+j][nt*16+ni])
// ---------------------------------------------------------------------------
__global__ void w2s_kernel(const float* __restrict__ W2f, unsigned short* __restrict__ W2s) {
  const int id = blockIdx.x * 512 + threadIdx.x;
  const int j = id & 7;
  const int ni = (id >> 3) & 15;
  const int q = (id >> 7) & 3;
  const int nt = (id >> 9) & 31;
  const int ks = id >> 14;
  const int k = ks * 32 + q * 8 + j;
  const int n = nt * 16 + ni;
  W2s[id] = f2bf(W2f[k * 512 + n]);
}

// ---------------------------------------------------------------------------
// Kernel 4: main fused kernel. Block = 512 thr (8 waves), BM=64, BN=512,
// BK=32 x 16 steps. Wave w owns N-slice [w*64, w*64+64).
// LDS: A dbuf 2x4KB, B dbuf 2x32KB, part 6KB = 78KB -> 2 blocks/CU.
// ---------------------------------------------------------------------------
__global__ __launch_bounds__(512, 4) void main_kernel(
    const float* __restrict__ Tx, const float* __restrict__ Ty,
    const float* __restrict__ tvec, const unsigned short* __restrict__ W2s,
    const float* __restrict__ b2f, const float* __restrict__ W3f,
    const float* __restrict__ b3f, float* __restrict__ out) {
  __shared__ __attribute__((aligned(16))) unsigned short Ab[2][64 * 32];   // 2x4KB
  __shared__ __attribute__((aligned(16))) unsigned short Bb[2][32 * 512];  // 2x32KB
  __shared__ float part[8][64][3];                                         // 6KB

  const int t = threadIdx.x;
  const int w = t >> 6;            // wave id 0..7  (N-slice)
  const int lane = t & 63;
  const int q = lane >> 4;         // k-quad / row-quad
  const int lr = lane & 15;
  const int x0 = blockIdx.x * 8, y0 = blockIdx.y * 8;

  // ---- A-staging mapping: thread t covers pixel p = t>>3, k-sub s = t&7
  // (4 consecutive k values s*4..s*4+3 of the 32-wide step).
  const int p = t >> 3, s = t & 7;
  const int xi = x0 + (p >> 3), yi = y0 + (p & 7);
  const float* txp = Tx + xi * 512;
  const float* typ = Ty + yi * 512;
  // frag-layout write slot: ((mt*4+q)*16+mr)*8 + j0,  q=s>>1, j0=(s&1)*4
  const int aslot = (((p >> 4) * 4 + (s >> 1)) * 16 + (p & 15)) * 8 + (s & 1) * 4;

  f32x4 acc[4][4];
#pragma unroll
  for (int i = 0; i < 4; ++i)
#pragma unroll
    for (int j2 = 0; j2 < 4; ++j2) acc[i][j2] = (f32x4){0.f, 0.f, 0.f, 0.f};

  // ---- prologue: stage step 0 into buffer 0 ----
  {
    const char* gsrc = (const char*)(W2s + 0 * 16384);
#pragma unroll
    for (int i = 0; i < 4; ++i) {
      const int off = (w * 4 + i) * 1024;
      gl_lds16(gsrc + off + lane * 16, ((char*)Bb[0]) + off);
    }
    const int kg = 0 * 32 + s * 4;
    float4 a = *(const float4*)(txp + kg);
    float4 b = *(const float4*)(typ + kg);
    float4 c = *(const float4*)(tvec + kg);
    uint2 pk;
    pk.x = (unsigned)f2bf(fmaxf(a.x + b.x + c.x, 0.f)) |
           ((unsigned)f2bf(fmaxf(a.y + b.y + c.y, 0.f)) << 16);
    pk.y = (unsigned)f2bf(fmaxf(a.z + b.z + c.z, 0.f)) |
           ((unsigned)f2bf(fmaxf(a.w + b.w + c.w, 0.f)) << 16);
    *(uint2*)&Ab[0][aslot] = pk;
  }

#pragma unroll
  for (int ks = 0; ks < 16; ++ks) {
    const int cb = ks & 1, nb = cb ^ 1;
    __syncthreads();  // publishes A(ks)/B(ks); drains B(ks) glds issued last iter

    // ---- issue B(ks+1) prefetch (in flight during this step's compute) ----
    if (ks < 15) {
      const char* gsrc = (const char*)(W2s + (ks + 1) * 16384);
#pragma unroll
      for (int i = 0; i < 4; ++i) {
        const int off = (w * 4 + i) * 1024;
        gl_lds16(gsrc + off + lane * 16, ((char*)Bb[nb]) + off);
      }
    }

    // ---- MFMA on buffers cb ----
    bf16x8 af[4];
#pragma unroll
    for (int mt = 0; mt < 4; ++mt)
      af[mt] = *(const bf16x8*)&Ab[cb][((mt * 4 + q) * 16 + lr) * 8];
#pragma unroll
    for (int nt = 0; nt < 4; ++nt) {
      bf16x8 bfr = *(const bf16x8*)&Bb[cb][(((w * 4 + nt) * 4 + q) * 16 + lr) * 8];
#pragma unroll
      for (int mt = 0; mt < 4; ++mt)
        acc[mt][nt] =
            __builtin_amdgcn_mfma_f32_16x16x32_bf16(af[mt], bfr, acc[mt][nt], 0, 0, 0);
    }

    // ---- compute + write A(ks+1) into the other buffer ----
    if (ks < 15) {
      const int kg = (ks + 1) * 32 + s * 4;
      float4 a = *(const float4*)(txp + kg);
      float4 b = *(const float4*)(typ + kg);
      float4 c = *(const float4*)(tvec + kg);
      uint2 pk;
      pk.x = (unsigned)f2bf(fmaxf(a.x + b.x + c.x, 0.f)) |
             ((unsigned)f2bf(fmaxf(a.y + b.y + c.y, 0.f)) << 16);
      pk.y = (unsigned)f2bf(fmaxf(a.z + b.z + c.z, 0.f)) |
             ((unsigned)f2bf(fmaxf(a.w + b.w + c.w, 0.f)) << 16);
      *(uint2*)&Ab[nb][aslot] = pk;
    }
  }

  // ---- epilogue: h2 = relu(acc + b2f); rgb partial = h2 @ W3f (k-slice) ----
  float w3v[4][3];
  float bb2[4];
#pragma unroll
  for (int nt = 0; nt < 4; ++nt) {
    const int k = w * 64 + nt * 16 + lr;
    bb2[nt] = b2f[k];
    w3v[nt][0] = W3f[k * 3 + 0];
    w3v[nt][1] = W3f[k * 3 + 1];
    w3v[nt][2] = W3f[k * 3 + 2];
  }
#pragma unroll
  for (int half = 0; half < 2; ++half) {
    float v[2][4][3];
#pragma unroll
    for (int mi = 0; mi < 2; ++mi)
#pragma unroll
      for (int r = 0; r < 4; ++r)
#pragma unroll
        for (int c = 0; c < 3; ++c) v[mi][r][c] = 0.f;
#pragma unroll
    for (int mi = 0; mi < 2; ++mi) {
      const int mt = half * 2 + mi;
#pragma unroll
      for (int r = 0; r < 4; ++r) {
#pragma unroll
        for (int nt = 0; nt < 4; ++nt) {
          float h2 = fmaxf(acc[mt][nt][r] + bb2[nt], 0.f);
          v[mi][r][0] += h2 * w3v[nt][0];
          v[mi][r][1] += h2 * w3v[nt][1];
          v[mi][r][2] += h2 * w3v[nt][2];
        }
      }
    }
#pragma unroll
    for (int d = 1; d < 16; d <<= 1) {
#pragma unroll
      for (int mi = 0; mi < 2; ++mi)
#pragma unroll
        for (int r = 0; r < 4; ++r)
#pragma unroll
          for (int c = 0; c < 3; ++c)
            v[mi][r][c] += __shfl_xor(v[mi][r][c], d, 64);
    }
    if (lr == 0) {
#pragma unroll
      for (int mi = 0; mi < 2; ++mi)
#pragma unroll
        for (int r = 0; r < 4; ++r) {
          const int row = (half * 2 + mi) * 16 + q * 4 + r;
#pragma unroll
          for (int c = 0; c < 3; ++c) part[w][row][c] = v[mi][r][c];
        }
    }
  }
  __syncthreads();
  // wave c (0..2) writes plane c: contiguous 8-float rows per pixel-row
  if (t < 192) {
    const int c = t >> 6, mm = t & 63;
    float sum = b3f[c];
#pragma unroll
    for (int ww = 0; ww < 8; ++ww) sum += part[ww][mm][c];
    const int n = (x0 + (mm >> 3)) * 512 + (y0 + (mm & 7));
    out[c * NPIX + n] = sum;
  }
}

// ---------------------------------------------------------------------------
// Inputs: 0 coords (unused), 1 W1p, 2 b1p, 3 W2p, 4 b2p, 5 W1f, 6 b1f,
//         7 W2f, 8 b2f, 9 W3f, 10 b3f, 11 idx
// ---------------------------------------------------------------------------
extern "C" void kernel_launch(void* const* d_in, const int* in_sizes, int n_in,
                              void* d_out, int out_size, void* d_ws, size_t ws_size,
                              hipStream_t stream) {
  const float* W1p = (const float*)d_in[1];
  const float* b1p = (const float*)d_in[2];
  const float* W2p = (const float*)d_in[3];
  const float* b2p = (const float*)d_in[4];
  const float* W1f = (const float*)d_in[5];
  const float* b1f = (const float*)d_in[6];
  const float* W2f = (const float*)d_in[7];
  const float* b2f = (const float*)d_in[8];
  const float* W3f = (const float*)d_in[9];
  const float* b3f = (const float*)d_in[10];
  const int* idx = (const int*)d_in[11];
  float* out = (float*)d_out;

  char* ws = (char*)d_ws;
  float* Tx = (float*)ws;                                   // 1 MB
  float* Ty = (float*)(ws + (1u << 20));                    // 1 MB
  float* tvec = (float*)(ws + (2u << 20));                  // 2 KB
  unsigned short* W2s = (unsigned short*)(ws + (2u << 20) + 8192);  // 512 KB

  hipLaunchKernelGGL(time_kernel, dim3(1), dim3(512), 0, stream,
                     W1p, b1p, W2p, b2p, W1f, b1f, idx, tvec);
  hipLaunchKernelGGL(tables_kernel, dim3(512), dim3(512), 0, stream, W1f, Tx, Ty);
  hipLaunchKernelGGL(w2s_kernel, dim3(512), dim3(512), 0, stream, W2f, W2s);
  hipLaunchKernelGGL(main_kernel, dim3(64, 64), dim3(512), 0, stream,
                     Tx, Ty, tvec, W2s, b2f, W3f, b3f, out);
}

// Round 4
// 299.754 us; speedup vs baseline: 2.2912x; 1.0137x over previous
//
#include <hip/hip_runtime.h>
#include <stdint.h>

// ---------------------------------------------------------------------------
// NIVR: coord-MLP over 512x512 grid.
//   time branch (exact fp32, 1 block)   -> tvec[512]
//   posenc tables (exact fp32)          -> Tx[512][512], Ty[512][512]
//   W2f -> bf16, pre-swizzled per-fragment image -> W2s
//   main: h1 = relu(Tx[x]+Ty[y]+tvec); layer2 via MFMA bf16 16x16x32;
//         fused layer3 epilogue via shuffles. Output [3][N].
//
// R4 = R3 with the B-stride bug fixed. W2s layout (w2s_kernel):
//   id = ks*16384 + nt*512 + q*128 + ni*8 + j   (shorts)
// so per-nt stride is 512 shorts (1KB) and per-ks stride 16384 shorts (32KB).
// R3 erroneously used nt*2048 / ks*65536 -> garbage B fragments.
//
// Structure (from R3):
//  - A tile (64x512 bf16, frag-swizzled, 64KB) computed into LDS ONCE before
//    the K-loop; single barrier before the epilogue.
//  - B never touches LDS: each wave reads only its own contiguous 1KB
//    fragment slabs, direct global->VGPR (coalesced dwordx4 from L2-resident
//    swizzled W2s) with a 1-step register double buffer. No barrier in the
//    K-loop => no vmcnt(0) drain => fine-grained vmcnt pipeline.
//  - K-loop: 4 glb loads + 4 ds_read_b128 + 16 MFMA per wave-step, x16.
//  - LDS 70KB -> 2 blocks/CU (16 waves, 4/SIMD).
// ---------------------------------------------------------------------------

typedef short bf16x8 __attribute__((ext_vector_type(8)));
typedef float f32x4 __attribute__((ext_vector_type(4)));

#define PI_F 3.14159265358979323846f
#define SIDE 512
#define NPIX (SIDE * SIDE)

__device__ __forceinline__ unsigned short f2bf(float f) {
  unsigned int u = __float_as_uint(f);
  u += 0x7fffu + ((u >> 16) & 1u);
  return (unsigned short)(u >> 16);
}

// ---------------------------------------------------------------------------
// Kernel 1: time branch (exact fp32).
// ---------------------------------------------------------------------------
__global__ void time_kernel(const float* __restrict__ W1p, const float* __restrict__ b1p,
                            const float* __restrict__ W2p, const float* __restrict__ b2p,
                            const float* __restrict__ W1f, const float* __restrict__ b1f,
                            const int* __restrict__ idx, float* __restrict__ tvec) {
  __shared__ float r_s[32];
  __shared__ float h_s[256];
  __shared__ float phi_s[128];
  const int t = threadIdx.x;
  const float tt = (float)idx[0] / 300.0f;
  if (t < 16) {
    float ang = tt * ldexpf(PI_F, t);
    r_s[t] = sinf(ang);
    r_s[16 + t] = cosf(ang);
  }
  __syncthreads();
  if (t < 256) {
    float a = b1p[t];
#pragma unroll
    for (int i = 0; i < 32; ++i) a += r_s[i] * W1p[i * 256 + t];
    h_s[t] = fmaxf(a, 0.f);
  }
  __syncthreads();
  if (t < 128) {
    float a = b2p[t];
    for (int i = 0; i < 256; ++i) a += h_s[i] * W2p[i * 128 + t];
    phi_s[t] = a;
  }
  __syncthreads();
  {
    float a = b1f[t];
    for (int p = 0; p < 128; ++p) a += phi_s[p] * W1f[(40 + p) * 512 + t];
    tvec[t] = a;
  }
}

// ---------------------------------------------------------------------------
// Kernel 2: posenc tables (exact fp32).
// ---------------------------------------------------------------------------
__global__ void tables_kernel(const float* __restrict__ W1f,
                              float* __restrict__ Tx, float* __restrict__ Ty) {
  __shared__ float enc[20];
  const int v = blockIdx.x, k = threadIdx.x;
  if (k < 10) {
    float u = (float)v / 512.0f;
    float ang = u * ldexpf(PI_F, k);
    enc[k] = sinf(ang);
    enc[10 + k] = cosf(ang);
  }
  __syncthreads();
  float ax = 0.f, ay = 0.f;
#pragma unroll
  for (int l = 0; l < 20; ++l) {
    ax += enc[l] * W1f[l * 512 + k];
    ay += enc[l] * W1f[(20 + l) * 512 + k];
  }
  Tx[v * 512 + k] = ax;
  Ty[v * 512 + k] = ay;
}

// ---------------------------------------------------------------------------
// Kernel 3: W2f -> bf16, per-fragment-swizzled image.
//   W2s[ks*16384 + nt*512 + q*128 + ni*8 + j] = bf16(W2f[ks*32+q*8+j][nt*16+ni])
// Lane l of the MFMA wave reads B frag (B[k=q*8+j][n=lr], q=l>>4, lr=l&15)
// for (ks, nt) as one coalesced dwordx4 at slab + l*16B.
// ---------------------------------------------------------------------------
__global__ void w2s_kernel(const float* __restrict__ W2f, unsigned short* __restrict__ W2s) {
  const int id = blockIdx.x * 512 + threadIdx.x;
  const int j = id & 7;
  const int ni = (id >> 3) & 15;
  const int q = (id >> 7) & 3;
  const int nt = (id >> 9) & 31;
  const int ks = id >> 14;
  const int k = ks * 32 + q * 8 + j;
  const int n = nt * 16 + ni;
  W2s[id] = f2bf(W2f[k * 512 + n]);
}

// ---------------------------------------------------------------------------
// Kernel 4: main fused kernel. Block = 512 thr (8 waves), BM=64, BN=512,
// K=512 in 16 steps of 32. Wave w owns N-slice [w*64, w*64+64).
// ---------------------------------------------------------------------------
__global__ __launch_bounds__(512, 4) void main_kernel(
    const float* __restrict__ Tx, const float* __restrict__ Ty,
    const float* __restrict__ tvec, const unsigned short* __restrict__ W2s,
    const float* __restrict__ b2f, const float* __restrict__ W3f,
    const float* __restrict__ b3f, float* __restrict__ out) {
  __shared__ __attribute__((aligned(16))) unsigned short Ab[16 * 2048];  // 64KB
  __shared__ float part[8][64][3];                                       // 6KB

  const int t = threadIdx.x;
  const int w = t >> 6;            // wave id 0..7  (N-slice)
  const int lane = t & 63;
  const int q = lane >> 4;
  const int lr = lane & 15;
  const int x0 = blockIdx.x * 8, y0 = blockIdx.y * 8;

  // per-wave B pointer: fragment slab (ks, nt) is 512 shorts (1KB);
  // wave w owns nt-slots w*4..w*4+3; lane reads at +lane*8 (16B).
  const unsigned short* bptr = W2s + (w * 4) * 512 + lane * 8;

  // ---- issue B(0) loads first so they fly during the A fill ----
  bf16x8 bcur[4], bnxt[4];
#pragma unroll
  for (int nt = 0; nt < 4; ++nt)
    bcur[nt] = *(const bf16x8*)(bptr + nt * 512);

  // ---- A fill: thread (p = t>>3, s = t&7) covers pixel p, k = ks*32+s*4..+3
  {
    const int p = t >> 3, s = t & 7;
    const int xi = x0 + (p >> 3), yi = y0 + (p & 7);
    const float* txp = Tx + xi * 512 + s * 4;
    const float* typ = Ty + yi * 512 + s * 4;
    const float* tvp = tvec + s * 4;
    const int abase = (((p >> 4) * 4 + (s >> 1)) * 16 + (p & 15)) * 8 + (s & 1) * 4;
#pragma unroll
    for (int ks = 0; ks < 16; ++ks) {
      float4 a = *(const float4*)(txp + ks * 32);
      float4 b = *(const float4*)(typ + ks * 32);
      float4 c = *(const float4*)(tvp + ks * 32);
      uint2 pk;
      pk.x = (unsigned)f2bf(fmaxf(a.x + b.x + c.x, 0.f)) |
             ((unsigned)f2bf(fmaxf(a.y + b.y + c.y, 0.f)) << 16);
      pk.y = (unsigned)f2bf(fmaxf(a.z + b.z + c.z, 0.f)) |
             ((unsigned)f2bf(fmaxf(a.w + b.w + c.w, 0.f)) << 16);
      *(uint2*)&Ab[ks * 2048 + abase] = pk;
    }
  }

  f32x4 acc[4][4];
#pragma unroll
  for (int i = 0; i < 4; ++i)
#pragma unroll
    for (int j2 = 0; j2 < 4; ++j2) acc[i][j2] = (f32x4){0.f, 0.f, 0.f, 0.f};

  __syncthreads();  // the only barrier before the epilogue

  // ---- barrier-free K-loop: 4 glb loads + 4 ds_read_b128 + 16 MFMA / step
#pragma unroll
  for (int ks = 0; ks < 16; ++ks) {
    if (ks < 15) {
#pragma unroll
      for (int nt = 0; nt < 4; ++nt)
        bnxt[nt] = *(const bf16x8*)(bptr + (ks + 1) * 16384 + nt * 512);
    }
    bf16x8 af[4];
#pragma unroll
    for (int mt = 0; mt < 4; ++mt)
      af[mt] = *(const bf16x8*)&Ab[ks * 2048 + mt * 512 + lane * 8];
#pragma unroll
    for (int nt = 0; nt < 4; ++nt)
#pragma unroll
      for (int mt = 0; mt < 4; ++mt)
        acc[mt][nt] =
            __builtin_amdgcn_mfma_f32_16x16x32_bf16(af[mt], bcur[nt], acc[mt][nt], 0, 0, 0);
#pragma unroll
    for (int nt = 0; nt < 4; ++nt) bcur[nt] = bnxt[nt];
  }

  // ---- epilogue: h2 = relu(acc + b2f); rgb partial = h2 @ W3f (k-slice) ----
  float w3v[4][3];
  float bb2[4];
#pragma unroll
  for (int nt = 0; nt < 4; ++nt) {
    const int k = w * 64 + nt * 16 + lr;
    bb2[nt] = b2f[k];
    w3v[nt][0] = W3f[k * 3 + 0];
    w3v[nt][1] = W3f[k * 3 + 1];
    w3v[nt][2] = W3f[k * 3 + 2];
  }
#pragma unroll
  for (int half = 0; half < 2; ++half) {
    float v[2][4][3];
#pragma unroll
    for (int mi = 0; mi < 2; ++mi)
#pragma unroll
      for (int r = 0; r < 4; ++r)
#pragma unroll
        for (int c = 0; c < 3; ++c) v[mi][r][c] = 0.f;
#pragma unroll
    for (int mi = 0; mi < 2; ++mi) {
      const int mt = half * 2 + mi;
#pragma unroll
      for (int r = 0; r < 4; ++r) {
#pragma unroll
        for (int nt = 0; nt < 4; ++nt) {
          float h2 = fmaxf(acc[mt][nt][r] + bb2[nt], 0.f);
          v[mi][r][0] += h2 * w3v[nt][0];
          v[mi][r][1] += h2 * w3v[nt][1];
          v[mi][r][2] += h2 * w3v[nt][2];
        }
      }
    }
#pragma unroll
    for (int d = 1; d < 16; d <<= 1) {
#pragma unroll
      for (int mi = 0; mi < 2; ++mi)
#pragma unroll
        for (int r = 0; r < 4; ++r)
#pragma unroll
          for (int c = 0; c < 3; ++c)
            v[mi][r][c] += __shfl_xor(v[mi][r][c], d, 64);
    }
    if (lr == 0) {
#pragma unroll
      for (int mi = 0; mi < 2; ++mi)
#pragma unroll
        for (int r = 0; r < 4; ++r) {
          const int row = (half * 2 + mi) * 16 + q * 4 + r;
#pragma unroll
          for (int c = 0; c < 3; ++c) part[w][row][c] = v[mi][r][c];
        }
    }
  }
  __syncthreads();
  if (t < 192) {
    const int c = t >> 6, mm = t & 63;
    float sum = b3f[c];
#pragma unroll
    for (int ww = 0; ww < 8; ++ww) sum += part[ww][mm][c];
    const int n = (x0 + (mm >> 3)) * 512 + (y0 + (mm & 7));
    out[c * NPIX + n] = sum;
  }
}

// ---------------------------------------------------------------------------
// Inputs: 0 coords (unused), 1 W1p, 2 b1p, 3 W2p, 4 b2p, 5 W1f, 6 b1f,
//         7 W2f, 8 b2f, 9 W3f, 10 b3f, 11 idx
// ---------------------------------------------------------------------------
extern "C" void kernel_launch(void* const* d_in, const int* in_sizes, int n_in,
                              void* d_out, int out_size, void* d_ws, size_t ws_size,
                              hipStream_t stream) {
  const float* W1p = (const float*)d_in[1];
  const float* b1p = (const float*)d_in[2];
  const float* W2p = (const float*)d_in[3];
  const float* b2p = (const float*)d_in[4];
  const float* W1f = (const float*)d_in[5];
  const float* b1f = (const float*)d_in[6];
  const float* W2f = (const float*)d_in[7];
  const float* b2f = (const float*)d_in[8];
  const float* W3f = (const float*)d_in[9];
  const float* b3f = (const float*)d_in[10];
  const int* idx = (const int*)d_in[11];
  float* out = (float*)d_out;

  char* ws = (char*)d_ws;
  float* Tx = (float*)ws;                                   // 1 MB
  float* Ty = (float*)(ws + (1u << 20));                    // 1 MB
  float* tvec = (float*)(ws + (2u << 20));                  // 2 KB
  unsigned short* W2s = (unsigned short*)(ws + (2u << 20) + 8192);  // 512 KB

  hipLaunchKernelGGL(time_kernel, dim3(1), dim3(512), 0, stream,
                     W1p, b1p, W2p, b2p, W1f, b1f, idx, tvec);
  hipLaunchKernelGGL(tables_kernel, dim3(512), dim3(512), 0, stream, W1f, Tx, Ty);
  hipLaunchKernelGGL(w2s_kernel, dim3(512), dim3(512), 0, stream, W2f, W2s);
  hipLaunchKernelGGL(main_kernel, dim3(64, 64), dim3(512), 0, stream,
                     Tx, Ty, tvec, W2s, b2f, W3f, b3f, out);
}

// Round 5
// 293.473 us; speedup vs baseline: 2.3402x; 1.0214x over previous
//
#include <hip/hip_runtime.h>
#include <stdint.h>

// ---------------------------------------------------------------------------
// NIVR: coord-MLP over 512x512 grid.
//   pre_kernel (fused): time branch -> tvec[512]; posenc tables -> Tx,Ty;
//                       W2f -> bf16 frag-swizzled W2s. All fp32-exact except
//                       the W2f->bf16 cast.
//   main: h1 = relu(Tx[x]+Ty[y]+tvec); layer2 via MFMA bf16 16x16x32;
//         fused layer3 epilogue via shuffles. Output [3][N].
//
// R5 changes vs R4 (243us, WRITE_SIZE 276MB = scratch spill, MfmaUtil 24%):
//  - __launch_bounds__(512,2): 256-reg budget. R4's (512,4) capped at 128 and
//    the K-loop live set (64 AGPR acc + 48 B/A frags + addr) spilled into the
//    hot loop (276MB scratch writes). 1 block/CU, 2 waves/SIMD; one-step B
//    register prefetch (~300cyc of MFMA issue) covers L2 latency.
//  - A-fill rewritten: thread owns fixed slot v=t&255 (pixel p, quad q) and
//    writes ds_write_b128 at v*16B — stride-1 across lanes, conflict-free
//    (was 4-way-conflicted b64: 6.29M conflict cycles).
//  - time/tables/w2s fused into one 1025-block pre_kernel (independent work).
// ---------------------------------------------------------------------------

typedef short bf16x8 __attribute__((ext_vector_type(8)));
typedef float f32x4 __attribute__((ext_vector_type(4)));

#define PI_F 3.14159265358979323846f
#define SIDE 512
#define NPIX (SIDE * SIDE)

__device__ __forceinline__ unsigned short f2bf(float f) {
  unsigned int u = __float_as_uint(f);
  u += 0x7fffu + ((u >> 16) & 1u);
  return (unsigned short)(u >> 16);
}

// ---------------------------------------------------------------------------
// Fused precompute kernel. Grid = 1025 blocks x 512 threads:
//   blocks 0..511   : posenc tables (v = blockIdx)
//   blocks 512..1023: W2f -> bf16 frag-swizzled W2s
//   block 1024      : time branch
// W2s layout: id = ks*16384 + nt*512 + q*128 + ni*8 + j  (shorts)
//   W2s[id] = bf16(W2f[ks*32 + q*8 + j][nt*16 + ni])
// ---------------------------------------------------------------------------
__global__ void pre_kernel(const float* __restrict__ W1p, const float* __restrict__ b1p,
                           const float* __restrict__ W2p, const float* __restrict__ b2p,
                           const float* __restrict__ W1f, const float* __restrict__ b1f,
                           const float* __restrict__ W2f, const int* __restrict__ idx,
                           float* __restrict__ tvec, float* __restrict__ Tx,
                           float* __restrict__ Ty, unsigned short* __restrict__ W2s) {
  __shared__ float sm[256 + 128 + 32];  // reused per branch
  const int b = blockIdx.x;
  const int t = threadIdx.x;

  if (b < 512) {
    // ---- posenc tables for coord value v = b ----
    float* enc = sm;  // [20]
    if (t < 10) {
      float u = (float)b / 512.0f;
      float ang = u * ldexpf(PI_F, t);
      enc[t] = sinf(ang);
      enc[10 + t] = cosf(ang);
    }
    __syncthreads();
    float ax = 0.f, ay = 0.f;
#pragma unroll
    for (int l = 0; l < 20; ++l) {
      ax += enc[l] * W1f[l * 512 + t];
      ay += enc[l] * W1f[(20 + l) * 512 + t];
    }
    Tx[b * 512 + t] = ax;
    Ty[b * 512 + t] = ay;
  } else if (b < 1024) {
    // ---- W2f -> bf16 swizzle ----
    const int id = (b - 512) * 512 + t;
    const int j = id & 7;
    const int ni = (id >> 3) & 15;
    const int q = (id >> 7) & 3;
    const int nt = (id >> 9) & 31;
    const int ks = id >> 14;
    const int k = ks * 32 + q * 8 + j;
    const int n = nt * 16 + ni;
    W2s[id] = f2bf(W2f[k * 512 + n]);
  } else {
    // ---- time branch ----
    float* r_s = sm;           // [32]
    float* h_s = sm + 32;      // [256]
    float* phi_s = sm + 288;   // [128]
    const float tt = (float)idx[0] / 300.0f;
    if (t < 16) {
      float ang = tt * ldexpf(PI_F, t);
      r_s[t] = sinf(ang);
      r_s[16 + t] = cosf(ang);
    }
    __syncthreads();
    if (t < 256) {
      float a = b1p[t];
#pragma unroll
      for (int i = 0; i < 32; ++i) a += r_s[i] * W1p[i * 256 + t];
      h_s[t] = fmaxf(a, 0.f);
    }
    __syncthreads();
    if (t < 128) {
      float a = b2p[t];
      for (int i = 0; i < 256; ++i) a += h_s[i] * W2p[i * 128 + t];
      phi_s[t] = a;
    }
    __syncthreads();
    {
      float a = b1f[t];
      for (int p = 0; p < 128; ++p) a += phi_s[p] * W1f[(40 + p) * 512 + t];
      tvec[t] = a;
    }
  }
}

// ---------------------------------------------------------------------------
// Main fused kernel. Block = 512 thr (8 waves), BM=64, BN=512,
// K=512 in 16 steps of 32. Wave w owns N-slice [w*64, w*64+64).
// LDS: A tile 64KB (frag-swizzled, filled once) + part 6KB.
// launch_bounds(512,2): 256-reg budget => no spill; 1 block/CU.
// ---------------------------------------------------------------------------
__global__ __launch_bounds__(512, 2) void main_kernel(
    const float* __restrict__ Tx, const float* __restrict__ Ty,
    const float* __restrict__ tvec, const unsigned short* __restrict__ W2s,
    const float* __restrict__ b2f, const float* __restrict__ W3f,
    const float* __restrict__ b3f, float* __restrict__ out) {
  __shared__ __attribute__((aligned(16))) unsigned short Ab[16 * 2048];  // 64KB
  __shared__ float part[8][64][3];                                       // 6KB

  const int t = threadIdx.x;
  const int w = t >> 6;            // wave id 0..7  (N-slice)
  const int lane = t & 63;
  const int q = lane >> 4;
  const int lr = lane & 15;
  const int x0 = blockIdx.x * 8, y0 = blockIdx.y * 8;

  // per-wave B pointer: fragment slab (ks, nt) is 512 shorts (1KB);
  // wave w owns nt-slots w*4..w*4+3; lane reads at +lane*8 (16B).
  const unsigned short* bptr = W2s + (w * 4) * 512 + lane * 8;

  // ---- issue B(0) loads first so they fly during the A fill ----
  bf16x8 bcur[4], bnxt[4];
#pragma unroll
  for (int nt = 0; nt < 4; ++nt)
    bcur[nt] = *(const bf16x8*)(bptr + nt * 512);

  // ---- A fill, conflict-free: thread owns slot v = t&255 -> (mt,q2,mr),
  // pixel p = mt*16+mr, k-quad q2; handles steps ks = (t>>8) + 2i, i=0..7.
  // Writes one ds_write_b128 per step at shorts [ks*2048 + v*8] (stride-1
  // 16B across lanes).
  {
    const int v = t & 255, g = t >> 8;
    const int p = ((v >> 6) << 4) + (v & 15);
    const int q2 = (v >> 4) & 3;
    const int xi = x0 + (p >> 3), yi = y0 + (p & 7);
    const float* txp = Tx + xi * 512 + q2 * 8;
    const float* typ = Ty + yi * 512 + q2 * 8;
    const float* tvp = tvec + q2 * 8;
    unsigned short* aw = &Ab[v * 8];
#pragma unroll
    for (int i = 0; i < 8; ++i) {
      const int ks = g + i * 2;
      const int ko = ks * 32;
      float4 a0 = *(const float4*)(txp + ko);
      float4 a1 = *(const float4*)(txp + ko + 4);
      float4 b0 = *(const float4*)(typ + ko);
      float4 b1 = *(const float4*)(typ + ko + 4);
      float4 c0 = *(const float4*)(tvp + ko);
      float4 c1 = *(const float4*)(tvp + ko + 4);
      uint4 pk;
      pk.x = (unsigned)f2bf(fmaxf(a0.x + b0.x + c0.x, 0.f)) |
             ((unsigned)f2bf(fmaxf(a0.y + b0.y + c0.y, 0.f)) << 16);
      pk.y = (unsigned)f2bf(fmaxf(a0.z + b0.z + c0.z, 0.f)) |
             ((unsigned)f2bf(fmaxf(a0.w + b0.w + c0.w, 0.f)) << 16);
      pk.z = (unsigned)f2bf(fmaxf(a1.x + b1.x + c1.x, 0.f)) |
             ((unsigned)f2bf(fmaxf(a1.y + b1.y + c1.y, 0.f)) << 16);
      pk.w = (unsigned)f2bf(fmaxf(a1.z + b1.z + c1.z, 0.f)) |
             ((unsigned)f2bf(fmaxf(a1.w + b1.w + c1.w, 0.f)) << 16);
      *(uint4*)(aw + ks * 2048) = pk;
    }
  }

  f32x4 acc[4][4];
#pragma unroll
  for (int i = 0; i < 4; ++i)
#pragma unroll
    for (int j2 = 0; j2 < 4; ++j2) acc[i][j2] = (f32x4){0.f, 0.f, 0.f, 0.f};

  __syncthreads();  // the only barrier before the epilogue

  // ---- barrier-free K-loop: 4 glb loads + 4 ds_read_b128 + 16 MFMA / step
#pragma unroll
  for (int ks = 0; ks < 16; ++ks) {
    if (ks < 15) {
#pragma unroll
      for (int nt = 0; nt < 4; ++nt)
        bnxt[nt] = *(const bf16x8*)(bptr + (ks + 1) * 16384 + nt * 512);
    }
    bf16x8 af[4];
#pragma unroll
    for (int mt = 0; mt < 4; ++mt)
      af[mt] = *(const bf16x8*)&Ab[ks * 2048 + mt * 512 + lane * 8];
#pragma unroll
    for (int nt = 0; nt < 4; ++nt)
#pragma unroll
      for (int mt = 0; mt < 4; ++mt)
        acc[mt][nt] =
            __builtin_amdgcn_mfma_f32_16x16x32_bf16(af[mt], bcur[nt], acc[mt][nt], 0, 0, 0);
#pragma unroll
    for (int nt = 0; nt < 4; ++nt) bcur[nt] = bnxt[nt];
  }

  // ---- epilogue: h2 = relu(acc + b2f); rgb partial = h2 @ W3f (k-slice) ----
  float w3v[4][3];
  float bb2[4];
#pragma unroll
  for (int nt = 0; nt < 4; ++nt) {
    const int k = w * 64 + nt * 16 + lr;
    bb2[nt] = b2f[k];
    w3v[nt][0] = W3f[k * 3 + 0];
    w3v[nt][1] = W3f[k * 3 + 1];
    w3v[nt][2] = W3f[k * 3 + 2];
  }
#pragma unroll
  for (int half = 0; half < 2; ++half) {
    float v[2][4][3];
#pragma unroll
    for (int mi = 0; mi < 2; ++mi)
#pragma unroll
      for (int r = 0; r < 4; ++r)
#pragma unroll
        for (int c = 0; c < 3; ++c) v[mi][r][c] = 0.f;
#pragma unroll
    for (int mi = 0; mi < 2; ++mi) {
      const int mt = half * 2 + mi;
#pragma unroll
      for (int r = 0; r < 4; ++r) {
#pragma unroll
        for (int nt = 0; nt < 4; ++nt) {
          float h2 = fmaxf(acc[mt][nt][r] + bb2[nt], 0.f);
          v[mi][r][0] += h2 * w3v[nt][0];
          v[mi][r][1] += h2 * w3v[nt][1];
          v[mi][r][2] += h2 * w3v[nt][2];
        }
      }
    }
#pragma unroll
    for (int d = 1; d < 16; d <<= 1) {
#pragma unroll
      for (int mi = 0; mi < 2; ++mi)
#pragma unroll
        for (int r = 0; r < 4; ++r)
#pragma unroll
          for (int c = 0; c < 3; ++c)
            v[mi][r][c] += __shfl_xor(v[mi][r][c], d, 64);
    }
    if (lr == 0) {
#pragma unroll
      for (int mi = 0; mi < 2; ++mi)
#pragma unroll
        for (int r = 0; r < 4; ++r) {
          const int row = (half * 2 + mi) * 16 + q * 4 + r;
#pragma unroll
          for (int c = 0; c < 3; ++c) part[w][row][c] = v[mi][r][c];
        }
    }
  }
  __syncthreads();
  if (t < 192) {
    const int c = t >> 6, mm = t & 63;
    float sum = b3f[c];
#pragma unroll
    for (int ww = 0; ww < 8; ++ww) sum += part[ww][mm][c];
    const int n = (x0 + (mm >> 3)) * 512 + (y0 + (mm & 7));
    out[c * NPIX + n] = sum;
  }
}

// ---------------------------------------------------------------------------
// Inputs: 0 coords (unused), 1 W1p, 2 b1p, 3 W2p, 4 b2p, 5 W1f, 6 b1f,
//         7 W2f, 8 b2f, 9 W3f, 10 b3f, 11 idx
// ---------------------------------------------------------------------------
extern "C" void kernel_launch(void* const* d_in, const int* in_sizes, int n_in,
                              void* d_out, int out_size, void* d_ws, size_t ws_size,
                              hipStream_t stream) {
  const float* W1p = (const float*)d_in[1];
  const float* b1p = (const float*)d_in[2];
  const float* W2p = (const float*)d_in[3];
  const float* b2p = (const float*)d_in[4];
  const float* W1f = (const float*)d_in[5];
  const float* b1f = (const float*)d_in[6];
  const float* W2f = (const float*)d_in[7];
  const float* b2f = (const float*)d_in[8];
  const float* W3f = (const float*)d_in[9];
  const float* b3f = (const float*)d_in[10];
  const int* idx = (const int*)d_in[11];
  float* out = (float*)d_out;

  char* ws = (char*)d_ws;
  float* Tx = (float*)ws;                                   // 1 MB
  float* Ty = (float*)(ws + (1u << 20));                    // 1 MB
  float* tvec = (float*)(ws + (2u << 20));                  // 2 KB
  unsigned short* W2s = (unsigned short*)(ws + (2u << 20) + 8192);  // 512 KB

  hipLaunchKernelGGL(pre_kernel, dim3(1025), dim3(512), 0, stream,
                     W1p, b1p, W2p, b2p, W1f, b1f, W2f, idx, tvec, Tx, Ty, W2s);
  hipLaunchKernelGGL(main_kernel, dim3(64, 64), dim3(512), 0, stream,
                     Tx, Ty, tvec, W2s, b2f, W3f, b3f, out);
}